// Round 1
// baseline (312.370 us; speedup 1.0000x reference)
//
#include <hip/hip_runtime.h>
#include <math.h>

#define Bb 8
#define Nn 64
#define Ff 32
#define Tt 4
#define OUTn 128

__device__ __forceinline__ float sigmoidf_(float x){ return 1.0f/(1.0f+expf(-x)); }

// ---- precompute wzxb = w_z . x + b_z, wcxb = w_c . x + b_c  (iteration-invariant) ----
__global__ __launch_bounds__(256) void precompute_wx(
    const float* __restrict__ x,
    const float* __restrict__ w_z,
    const float* __restrict__ w_c,
    const float* __restrict__ b_z,
    const float* __restrict__ b_c,
    float* __restrict__ wzxb,
    float* __restrict__ wcxb) {
  int jc = blockIdx.x;    // 0..7 (j chunk)
  int i  = blockIdx.y;    // 0..63
  int t  = threadIdx.x;   // 256
  __shared__ __align__(16) float xL[Bb][Ff];
  {
    int b = t >> 5, g = t & 31;
    xL[b][g] = x[(b*Nn + i)*Ff + g];
  }
  __syncthreads();
  int jj = t >> 5;        // 0..7
  int j  = jc*8 + jj;
  int f  = t & 31;
  const float4* wz4 = (const float4*)&w_z[(((size_t)i*Nn + j)*Ff + f)*Ff];
  const float4* wc4 = (const float4*)&w_c[(((size_t)i*Nn + j)*Ff + f)*Ff];
  float4 az[8], ac[8];
#pragma unroll
  for (int q=0;q<8;++q){ az[q]=wz4[q]; ac[q]=wc4[q]; }
  float bzf = b_z[f], bcf = b_c[f];
#pragma unroll
  for (int b=0;b<Bb;++b){
    const float4* xr = (const float4*)xL[b];
    float sz = 0.f, sc = 0.f;
#pragma unroll
    for (int q=0;q<8;++q){
      float4 xv = xr[q];
      sz = fmaf(az[q].x, xv.x, sz); sz = fmaf(az[q].y, xv.y, sz);
      sz = fmaf(az[q].z, xv.z, sz); sz = fmaf(az[q].w, xv.w, sz);
      sc = fmaf(ac[q].x, xv.x, sc); sc = fmaf(ac[q].y, xv.y, sc);
      sc = fmaf(ac[q].z, xv.z, sc); sc = fmaf(ac[q].w, xv.w, sc);
    }
    wzxb[((b*Nn + i)*Nn + j)*Ff + f] = sz + bzf;
    wcxb[((b*Nn + i)*Nn + j)*Ff + f] = sc + bcf;
  }
}

// ---- one message-passing iteration: reads mfp (prev m_full), writes mfn ----
__global__ __launch_bounds__(256) void mp_iter(
    const float* __restrict__ A,
    const float* __restrict__ u_z,
    const float* __restrict__ u_c,
    const float* __restrict__ wzxb,
    const float* __restrict__ wcxb,
    const float* __restrict__ mfp,
    float* __restrict__ mfn,
    int first) {
  int b = blockIdx.x;  // 8
  int i = blockIdx.y;  // 64
  int tid = threadIdx.x;

  __shared__ __align__(16) float Mc [Nn][Ff];  // compact neighbor rows of M
  __shared__ __align__(16) float mo [Nn][Ff];  // m_other
  __shared__ __align__(16) float gsL[Nn][Ff];  // gated_sum
  __shared__ __align__(16) float rmL[Nn][Ff];  // r_msg
  __shared__ __align__(16) float zL [Nn][Ff];  // z
  __shared__ float aggL[Ff];
  __shared__ int nbrL[Nn];
  __shared__ int nnL;

  // build neighbor list from A row (A is exactly 0/1)
  if (tid < 64) {
    float a = A[(b*Nn + i)*Nn + tid];
    unsigned long long m = __ballot(a != 0.0f);
    if (a != 0.0f) {
      int pos = __popcll(m & ((1ull << tid) - 1ull));
      nbrL[pos] = tid;
    }
    if (tid == 0) nnL = __popcll(m);
  }
  __syncthreads();
  int nn = nnL;
  int P = nn * Ff;

  // load compact M rows: M[k] = A[i,k]*m_full_prev[max(i,k),min(i,k)]
  for (int idx = tid; idx < P; idx += 256) {
    int s = idx >> 5, f = idx & 31;
    int k = nbrL[s];
    int hi = max(i,k), lo = min(i,k);
    Mc[s][f] = first ? 0.0f : mfp[((b*Nn + hi)*Nn + lo)*Ff + f];
  }
  __syncthreads();
  // agg[f] = sum_k M[k,f]  (A factor already inside M; skipped k's are exact zeros)
  if (tid < Ff) {
    float s = 0.f;
    for (int s2 = 0; s2 < nn; ++s2) s += Mc[s2][tid];
    aggL[tid] = s;
  }
  __syncthreads();
  for (int idx = tid; idx < P; idx += 256) {
    int s = idx >> 5, f = idx & 31;
    mo[s][f] = aggL[f] - Mc[s][f];
  }
  __syncthreads();

  // pass A: z and gated_sum (the dominant gate loop)
  for (int p = tid; p < P; p += 256) {
    int s = p >> 5, f = p & 31;
    int j = nbrL[s];
    const float4* uz4 = (const float4*)&u_z[(((size_t)i*Nn + j)*Ff + f)*Ff];
    float4 u[8];
#pragma unroll
    for (int q=0;q<8;++q) u[q] = uz4[q];
    float wb = wzxb[((b*Nn + i)*Nn + j)*Ff + f];   // wzx + b_z
    // z = sigmoid(wzx + u_z . m_other + b_z)
    {
      float d = 0.f;
      const float4* mrow = (const float4*)mo[s];
#pragma unroll
      for (int q=0;q<8;++q){
        float4 m = mrow[q];
        d = fmaf(u[q].x,m.x,d); d = fmaf(u[q].y,m.y,d);
        d = fmaf(u[q].z,m.z,d); d = fmaf(u[q].w,m.w,d);
      }
      zL[s][f] = sigmoidf_(wb + d);
    }
    float gs = 0.f;
    for (int s2 = 0; s2 < nn; ++s2) {
      float dd = 0.f;
      const float4* m2 = (const float4*)Mc[s2];
#pragma unroll
      for (int q=0;q<8;++q){
        float4 m = m2[q];
        dd = fmaf(u[q].x,m.x,dd); dd = fmaf(u[q].y,m.y,dd);
        dd = fmaf(u[q].z,m.z,dd); dd = fmaf(u[q].w,m.w,dd);
      }
      float v = wb + dd;
      // gate = floorf(sigmoid_f32(v)) == 1 iff fp32 sigmoid rounds to exactly 1.0
      if (s2 != s && v >= 16.0f) {
        if (v > 17.5f || sigmoidf_(v) >= 1.0f) gs += Mc[s2][f];
      }
    }
    gsL[s][f] = gs;
  }
  __syncthreads();

  // pass B: r_msg = u_c . gated_sum
  for (int p = tid; p < P; p += 256) {
    int s = p >> 5, f = p & 31;
    int j = nbrL[s];
    const float4* uc4 = (const float4*)&u_c[(((size_t)i*Nn + j)*Ff + f)*Ff];
    float d = 0.f;
    const float4* g4 = (const float4*)gsL[s];
#pragma unroll
    for (int q=0;q<8;++q){
      float4 uu = uc4[q]; float4 m = g4[q];
      d = fmaf(uu.x,m.x,d); d = fmaf(uu.y,m.y,d);
      d = fmaf(uu.z,m.z,d); d = fmaf(uu.w,m.w,d);
    }
    rmL[s][f] = d;
  }
  __syncthreads();

  // pass C: cur = tanh(wcx + u_c . r_msg + b_c); m_full = (1-z)*m_other + z*cur
  for (int p = tid; p < P; p += 256) {
    int s = p >> 5, f = p & 31;
    int j = nbrL[s];
    const float4* uc4 = (const float4*)&u_c[(((size_t)i*Nn + j)*Ff + f)*Ff];
    float d = 0.f;
    const float4* r4 = (const float4*)rmL[s];
#pragma unroll
    for (int q=0;q<8;++q){
      float4 uu = uc4[q]; float4 m = r4[q];
      d = fmaf(uu.x,m.x,d); d = fmaf(uu.y,m.y,d);
      d = fmaf(uu.z,m.z,d); d = fmaf(uu.w,m.w,d);
    }
    float wc  = wcxb[((b*Nn + i)*Nn + j)*Ff + f];  // wcx + b_c
    float cur = tanhf(wc + d);
    float z   = zL[s][f];
    float mf  = (1.0f - z)*mo[s][f] + z*cur;
    mfn[((b*Nn + i)*Nn + j)*Ff + f] = mf;
  }
}

// ---- final: msg_sum, enc = relu(u_node.x + u_msg.msg_sum) ----
__global__ void finalize_enc(const float* __restrict__ x,
                             const float* __restrict__ A,
                             const float* __restrict__ mf,
                             const float* __restrict__ u_node,
                             const float* __restrict__ u_msg,
                             float* __restrict__ enc) {
  int b = blockIdx.x, i = blockIdx.y;
  int lane = threadIdx.x;  // 64
  __shared__ float xL[Ff], msgL[Ff], aL[Nn];
  if (lane < Nn) aL[lane] = A[(b*Nn + i)*Nn + lane];
  if (lane < Ff) xL[lane] = x[(b*Nn + i)*Ff + lane];
  __syncthreads();
  if (lane < Ff) {
    int f = lane;
    float m = 0.f;
    for (int k = 0; k < Nn; ++k) {
      if (aL[k] != 0.0f) {
        int hi = max(i,k), lo = min(i,k);
        m += mf[((b*Nn + hi)*Nn + lo)*Ff + f];
      }
    }
    msgL[f] = m;
  }
  __syncthreads();
  if (lane < Ff) {
    int f = lane;
    float an = 0.f, am = 0.f;
    for (int g = 0; g < Ff; ++g) {
      an = fmaf(u_node[((size_t)i*Ff + f)*Ff + g], xL[g],   an);
      am = fmaf(u_msg [((size_t)i*Ff + f)*Ff + g], msgL[g], am);
    }
    enc[b*(Nn*Ff) + i*Ff + f] = fmaxf(an + am, 0.0f);
  }
}

// ---- output linear + sigmoid ----
__global__ void linear_out(const float* __restrict__ enc,
                           const float* __restrict__ lin_w,
                           const float* __restrict__ lin_b,
                           float* __restrict__ out) {
  int b = blockIdx.x;   // 8
  int o = threadIdx.x;  // 128
  __shared__ __align__(16) float eL[Nn*Ff];
  for (int c = o; c < Nn*Ff; c += 128) eL[c] = enc[b*Nn*Ff + c];
  __syncthreads();
  float acc = lin_b[o];
  const float4* w4 = (const float4*)&lin_w[(size_t)o*Nn*Ff];
  const float4* e4 = (const float4*)eL;
  for (int q = 0; q < (Nn*Ff)/4; ++q) {
    float4 w = w4[q], e = e4[q];
    acc = fmaf(w.x,e.x,acc); acc = fmaf(w.y,e.y,acc);
    acc = fmaf(w.z,e.z,acc); acc = fmaf(w.w,e.w,acc);
  }
  out[b*OUTn + o] = 1.0f/(1.0f+expf(-acc));
}

extern "C" void kernel_launch(void* const* d_in, const int* in_sizes, int n_in,
                              void* d_out, int out_size, void* d_ws, size_t ws_size,
                              hipStream_t stream) {
  const float* x      = (const float*)d_in[0];
  const float* A      = (const float*)d_in[1];
  const float* w_z    = (const float*)d_in[2];
  const float* w_c    = (const float*)d_in[3];
  const float* u_z    = (const float*)d_in[4];
  const float* u_c    = (const float*)d_in[5];
  const float* b_z    = (const float*)d_in[6];
  const float* b_c    = (const float*)d_in[7];
  const float* u_node = (const float*)d_in[8];
  const float* u_msg  = (const float*)d_in[9];
  const float* lin_w  = (const float*)d_in[10];
  const float* lin_b  = (const float*)d_in[11];
  float* out = (float*)d_out;
  float* ws  = (float*)d_ws;

  const size_t SZ = (size_t)Bb*Nn*Nn*Ff;  // 1,048,576 floats
  float* wzxb = ws;
  float* wcxb = ws + SZ;
  float* mf0  = ws + 2*SZ;
  float* mf1  = ws + 3*SZ;
  float* enc  = ws + 4*SZ;

  precompute_wx<<<dim3(8, Nn), 256, 0, stream>>>(x, w_z, w_c, b_z, b_c, wzxb, wcxb);

  const float* rd = mf0; float* wr = mf1;
  for (int t = 0; t < Tt; ++t) {
    mp_iter<<<dim3(Bb, Nn), 256, 0, stream>>>(A, u_z, u_c, wzxb, wcxb, rd, wr, t == 0 ? 1 : 0);
    float* tmp = (float*)rd; rd = wr; wr = tmp;
  }
  // rd now points at the last-written m_full buffer
  finalize_enc<<<dim3(Bb, Nn), 64, 0, stream>>>(x, A, rd, u_node, u_msg, enc);
  linear_out<<<Bb, 128, 0, stream>>>(enc, lin_w, lin_b, out);
}

// Round 2
// 270.781 us; speedup vs baseline: 1.1536x; 1.1536x over previous
//
#include <hip/hip_runtime.h>
#include <math.h>

#define Bb 8
#define Nn 64
#define Ff 32
#define Tt 4
#define OUTn 128

__device__ __forceinline__ float sigmoidf_(float x){ return 1.0f/(1.0f+expf(-x)); }

// ---- precompute wzxb = w_z.x + b_z, wcxb = w_c.x + b_c, uznorm = ||u_z row||  ----
__global__ __launch_bounds__(256) void precompute_wx(
    const float* __restrict__ x,
    const float* __restrict__ w_z,
    const float* __restrict__ w_c,
    const float* __restrict__ u_z,
    const float* __restrict__ b_z,
    const float* __restrict__ b_c,
    float* __restrict__ wzxb,
    float* __restrict__ wcxb,
    float* __restrict__ uznorm) {
  int jc = blockIdx.x;    // 0..7 (j chunk)
  int i  = blockIdx.y;    // 0..63
  int t  = threadIdx.x;   // 256
  __shared__ __align__(16) float xL[Bb][Ff];
  {
    int b = t >> 5, g = t & 31;
    xL[b][g] = x[(b*Nn + i)*Ff + g];
  }
  __syncthreads();
  int jj = t >> 5;        // 0..7
  int j  = jc*8 + jj;
  int f  = t & 31;

  // u_z row norm (iteration-invariant screening bound)
  {
    const float4* u4 = (const float4*)&u_z[(((size_t)i*Nn + j)*Ff + f)*Ff];
    float ss = 0.f;
#pragma unroll
    for (int q=0;q<8;++q){
      float4 v = u4[q];
      ss = fmaf(v.x,v.x,ss); ss = fmaf(v.y,v.y,ss);
      ss = fmaf(v.z,v.z,ss); ss = fmaf(v.w,v.w,ss);
    }
    uznorm[(i*Nn + j)*Ff + f] = sqrtf(ss);
  }

  const float4* wz4 = (const float4*)&w_z[(((size_t)i*Nn + j)*Ff + f)*Ff];
  const float4* wc4 = (const float4*)&w_c[(((size_t)i*Nn + j)*Ff + f)*Ff];
  float4 az[8], ac[8];
#pragma unroll
  for (int q=0;q<8;++q){ az[q]=wz4[q]; ac[q]=wc4[q]; }
  float bzf = b_z[f], bcf = b_c[f];
#pragma unroll
  for (int b=0;b<Bb;++b){
    const float4* xr = (const float4*)xL[b];
    float sz = 0.f, sc = 0.f;
#pragma unroll
    for (int q=0;q<8;++q){
      float4 xv = xr[q];
      sz = fmaf(az[q].x, xv.x, sz); sz = fmaf(az[q].y, xv.y, sz);
      sz = fmaf(az[q].z, xv.z, sz); sz = fmaf(az[q].w, xv.w, sz);
      sc = fmaf(ac[q].x, xv.x, sc); sc = fmaf(ac[q].y, xv.y, sc);
      sc = fmaf(ac[q].z, xv.z, sc); sc = fmaf(ac[q].w, xv.w, sc);
    }
    wzxb[((b*Nn + i)*Nn + j)*Ff + f] = sz + bzf;
    wcxb[((b*Nn + i)*Nn + j)*Ff + f] = sc + bcf;
  }
}

// ---- one message-passing iteration with Cauchy-Schwarz gate screening ----
__global__ __launch_bounds__(256) void mp_iter(
    const float* __restrict__ A,
    const float* __restrict__ u_z,
    const float* __restrict__ u_c,
    const float* __restrict__ wzxb,
    const float* __restrict__ wcxb,
    const float* __restrict__ uznorm,
    const float* __restrict__ mfp,
    float* __restrict__ mfn,
    int first) {
  int b = blockIdx.x;  // 8
  int i = blockIdx.y;  // 64
  int tid = threadIdx.x;

  __shared__ __align__(16) float Mc [Nn][Ff];  // compact neighbor rows of M
  __shared__ __align__(16) float mo [Nn][Ff];  // m_other
  __shared__ __align__(16) float gsL[Nn][Ff];  // gated_sum
  __shared__ __align__(16) float rmL[Nn][Ff];  // r_msg (slow path only)
  __shared__ float aggL[Ff];
  __shared__ float mnormL[Nn];
  __shared__ float mnmaxL;
  __shared__ int nbrL[Nn];
  __shared__ int nnL;
  __shared__ int anyGate;

  // build neighbor list from A row (A is exactly 0/1)
  if (tid < 64) {
    float a = A[(b*Nn + i)*Nn + tid];
    unsigned long long m = __ballot(a != 0.0f);
    if (a != 0.0f) {
      int pos = __popcll(m & ((1ull << tid) - 1ull));
      nbrL[pos] = tid;
    }
    if (tid == 0) { nnL = __popcll(m); anyGate = 0; }
  }
  __syncthreads();
  int nn = nnL;
  int P = nn * Ff;

  // load compact M rows: M[k] = A[i,k]*m_full_prev[max(i,k),min(i,k)]
  for (int idx = tid; idx < P; idx += 256) {
    int s = idx >> 5, f = idx & 31;
    int k = nbrL[s];
    int hi = max(i,k), lo = min(i,k);
    Mc[s][f] = first ? 0.0f : mfp[((b*Nn + hi)*Nn + lo)*Ff + f];
  }
  __syncthreads();
  // agg[f] = sum_k M[k,f]
  if (tid < Ff) {
    float s = 0.f;
    for (int s2 = 0; s2 < nn; ++s2) s += Mc[s2][tid];
    aggL[tid] = s;
  }
  // per-row norms of M (screening)
  if (tid >= 64 && tid < 128) {
    int s = tid - 64;
    if (s < nn) {
      float ss = 0.f;
      for (int f = 0; f < Ff; ++f) { float v = Mc[s][f]; ss = fmaf(v,v,ss); }
      mnormL[s] = sqrtf(ss);
    }
  }
  __syncthreads();
  if (tid == 0) {
    float m = 0.f;
    for (int s = 0; s < nn; ++s) m = fmaxf(m, mnormL[s]);
    mnmaxL = m;
  }
  for (int idx = tid; idx < P; idx += 256) {
    int s = idx >> 5, f = idx & 31;
    mo[s][f] = aggL[f] - Mc[s][f];
  }
  __syncthreads();
  float mnmax = mnmaxL;

  // pass A: z (always) + gated_sum (screened)
  float zR[8];
  int lany = 0;
#pragma unroll
  for (int q = 0; q < 8; ++q) {
    int p = tid + q*256;
    if (p < P) {
      int s = p >> 5, f = p & 31;
      int j = nbrL[s];
      const float4* uz4 = (const float4*)&u_z[(((size_t)i*Nn + j)*Ff + f)*Ff];
      float4 u[8];
#pragma unroll
      for (int qq=0;qq<8;++qq) u[qq] = uz4[qq];
      float wb = wzxb[((b*Nn + i)*Nn + j)*Ff + f];   // wzx + b_z
      // z = sigmoid(wzx + u_z . m_other + b_z)
      {
        float d = 0.f;
        const float4* mrow = (const float4*)mo[s];
#pragma unroll
        for (int qq=0;qq<8;++qq){
          float4 m = mrow[qq];
          d = fmaf(u[qq].x,m.x,d); d = fmaf(u[qq].y,m.y,d);
          d = fmaf(u[qq].z,m.z,d); d = fmaf(u[qq].w,m.w,d);
        }
        zR[q] = sigmoidf_(wb + d);
      }
      float gs = 0.f;
      float un = uznorm[(i*Nn + j)*Ff + f];
      // gate can be nonzero only if fp32 sigmoid rounds to 1.0, i.e. v >= ~16.6.
      // |dot| <= ||u_row||*||M_k|| (Cauchy-Schwarz); 0.5 margin covers all fp32
      // rounding (ours and the reference's). Survivors take the exact path.
      if (wb + un * mnmax >= 15.5f) {
        for (int s2 = 0; s2 < nn; ++s2) {
          if (s2 == s) continue;
          if (wb + un * mnormL[s2] < 15.5f) continue;
          float dd = 0.f;
          const float4* m2 = (const float4*)Mc[s2];
#pragma unroll
          for (int qq=0;qq<8;++qq){
            float4 m = m2[qq];
            dd = fmaf(u[qq].x,m.x,dd); dd = fmaf(u[qq].y,m.y,dd);
            dd = fmaf(u[qq].z,m.z,dd); dd = fmaf(u[qq].w,m.w,dd);
          }
          float v = wb + dd;
          if (v >= 16.0f && (v > 17.5f || sigmoidf_(v) >= 1.0f)) gs += Mc[s2][f];
        }
      }
      if (gs != 0.0f) lany = 1;
      gsL[s][f] = gs;
    }
  }
  if (lany) atomicOr(&anyGate, 1);
  __syncthreads();

  if (anyGate) {
    // slow path (bit-exact round-0 passes B & C)
    for (int p = tid; p < P; p += 256) {
      int s = p >> 5, f = p & 31;
      int j = nbrL[s];
      const float4* uc4 = (const float4*)&u_c[(((size_t)i*Nn + j)*Ff + f)*Ff];
      float d = 0.f;
      const float4* g4 = (const float4*)gsL[s];
#pragma unroll
      for (int qq=0;qq<8;++qq){
        float4 uu = uc4[qq]; float4 m = g4[qq];
        d = fmaf(uu.x,m.x,d); d = fmaf(uu.y,m.y,d);
        d = fmaf(uu.z,m.z,d); d = fmaf(uu.w,m.w,d);
      }
      rmL[s][f] = d;
    }
    __syncthreads();
#pragma unroll
    for (int q = 0; q < 8; ++q) {
      int p = tid + q*256;
      if (p < P) {
        int s = p >> 5, f = p & 31;
        int j = nbrL[s];
        const float4* uc4 = (const float4*)&u_c[(((size_t)i*Nn + j)*Ff + f)*Ff];
        float d = 0.f;
        const float4* r4 = (const float4*)rmL[s];
#pragma unroll
        for (int qq=0;qq<8;++qq){
          float4 uu = uc4[qq]; float4 m = r4[qq];
          d = fmaf(uu.x,m.x,d); d = fmaf(uu.y,m.y,d);
          d = fmaf(uu.z,m.z,d); d = fmaf(uu.w,m.w,d);
        }
        size_t idx = ((size_t)(b*Nn + i)*Nn + j)*Ff + f;
        float cur = tanhf(wcxb[idx] + d);
        float z   = zR[q];
        mfn[idx] = (1.0f - z)*mo[s][f] + z*cur;
      }
    }
  } else {
    // fast path: gated_sum == 0 everywhere -> r_msg == 0 exactly ->
    // cur = tanh(wcxb). Bitwise identical to the full computation.
#pragma unroll
    for (int q = 0; q < 8; ++q) {
      int p = tid + q*256;
      if (p < P) {
        int s = p >> 5, f = p & 31;
        int j = nbrL[s];
        size_t idx = ((size_t)(b*Nn + i)*Nn + j)*Ff + f;
        float cur = tanhf(wcxb[idx]);
        float z   = zR[q];
        mfn[idx] = (1.0f - z)*mo[s][f] + z*cur;
      }
    }
  }
}

// ---- final: msg_sum, enc = relu(u_node.x + u_msg.msg_sum) ----
__global__ void finalize_enc(const float* __restrict__ x,
                             const float* __restrict__ A,
                             const float* __restrict__ mf,
                             const float* __restrict__ u_node,
                             const float* __restrict__ u_msg,
                             float* __restrict__ enc) {
  int b = blockIdx.x, i = blockIdx.y;
  int lane = threadIdx.x;  // 64
  __shared__ float xL[Ff], msgL[Ff], aL[Nn];
  if (lane < Nn) aL[lane] = A[(b*Nn + i)*Nn + lane];
  if (lane < Ff) xL[lane] = x[(b*Nn + i)*Ff + lane];
  __syncthreads();
  if (lane < Ff) {
    int f = lane;
    float m = 0.f;
    for (int k = 0; k < Nn; ++k) {
      if (aL[k] != 0.0f) {
        int hi = max(i,k), lo = min(i,k);
        m += mf[((b*Nn + hi)*Nn + lo)*Ff + f];
      }
    }
    msgL[f] = m;
  }
  __syncthreads();
  if (lane < Ff) {
    int f = lane;
    float an = 0.f, am = 0.f;
    for (int g = 0; g < Ff; ++g) {
      an = fmaf(u_node[((size_t)i*Ff + f)*Ff + g], xL[g],   an);
      am = fmaf(u_msg [((size_t)i*Ff + f)*Ff + g], msgL[g], am);
    }
    enc[b*(Nn*Ff) + i*Ff + f] = fmaxf(an + am, 0.0f);
  }
}

// ---- output linear + sigmoid ----
__global__ void linear_out(const float* __restrict__ enc,
                           const float* __restrict__ lin_w,
                           const float* __restrict__ lin_b,
                           float* __restrict__ out) {
  int b = blockIdx.x;   // 8
  int o = threadIdx.x;  // 128
  __shared__ __align__(16) float eL[Nn*Ff];
  for (int c = o; c < Nn*Ff; c += 128) eL[c] = enc[b*Nn*Ff + c];
  __syncthreads();
  float acc = lin_b[o];
  const float4* w4 = (const float4*)&lin_w[(size_t)o*Nn*Ff];
  const float4* e4 = (const float4*)eL;
  for (int q = 0; q < (Nn*Ff)/4; ++q) {
    float4 w = w4[q], e = e4[q];
    acc = fmaf(w.x,e.x,acc); acc = fmaf(w.y,e.y,acc);
    acc = fmaf(w.z,e.z,acc); acc = fmaf(w.w,e.w,acc);
  }
  out[b*OUTn + o] = 1.0f/(1.0f+expf(-acc));
}

extern "C" void kernel_launch(void* const* d_in, const int* in_sizes, int n_in,
                              void* d_out, int out_size, void* d_ws, size_t ws_size,
                              hipStream_t stream) {
  const float* x      = (const float*)d_in[0];
  const float* A      = (const float*)d_in[1];
  const float* w_z    = (const float*)d_in[2];
  const float* w_c    = (const float*)d_in[3];
  const float* u_z    = (const float*)d_in[4];
  const float* u_c    = (const float*)d_in[5];
  const float* b_z    = (const float*)d_in[6];
  const float* b_c    = (const float*)d_in[7];
  const float* u_node = (const float*)d_in[8];
  const float* u_msg  = (const float*)d_in[9];
  const float* lin_w  = (const float*)d_in[10];
  const float* lin_b  = (const float*)d_in[11];
  float* out = (float*)d_out;
  float* ws  = (float*)d_ws;

  const size_t SZ = (size_t)Bb*Nn*Nn*Ff;  // 1,048,576 floats
  float* wzxb   = ws;
  float* wcxb   = ws + SZ;
  float* mf0    = ws + 2*SZ;
  float* mf1    = ws + 3*SZ;
  float* enc    = ws + 4*SZ;
  float* uznorm = ws + 4*SZ + (size_t)Bb*Nn*Ff;  // 64*64*32 floats

  precompute_wx<<<dim3(8, Nn), 256, 0, stream>>>(x, w_z, w_c, u_z, b_z, b_c,
                                                 wzxb, wcxb, uznorm);

  const float* rd = mf0; float* wr = mf1;
  for (int t = 0; t < Tt; ++t) {
    mp_iter<<<dim3(Bb, Nn), 256, 0, stream>>>(A, u_z, u_c, wzxb, wcxb, uznorm,
                                              rd, wr, t == 0 ? 1 : 0);
    float* tmp = (float*)rd; rd = wr; wr = tmp;
  }
  finalize_enc<<<dim3(Bb, Nn), 64, 0, stream>>>(x, A, rd, u_node, u_msg, enc);
  linear_out<<<Bb, 128, 0, stream>>>(enc, lin_w, lin_b, out);
}